// Round 19
// baseline (47.047 us; speedup 1.0000x reference)
//
#include <hip/hip_runtime.h>

#define NN    16384
#define CBN   64
#define SUBV  16
#define KCODE 16
#define DOUTN 1024
#define DEP   4

typedef int   i32x4  __attribute__((ext_vector_type(4)));
typedef int   i32x16 __attribute__((ext_vector_type(16)));

// global -> LDS direct copy, 16B/lane. LDS dest wave-uniform (HW adds lane*16).
static __device__ __forceinline__ void gld16(const void* g, void* l) {
  __builtin_amdgcn_global_load_lds(
      (const __attribute__((address_space(1))) unsigned int*)g,
      (__attribute__((address_space(3))) unsigned int*)(uintptr_t)l, 16, 0, 0);
}

// ---------------- kernel 1: i8 table quantize + encode (R17 verbatim) -------
__global__ __launch_bounds__(256) void prep_k(
    const float* __restrict__ x, const int* __restrict__ split_idxs,
    const float* __restrict__ split_vals, const float* __restrict__ Tg,
    unsigned char* __restrict__ codes, unsigned char* __restrict__ img,
    float* __restrict__ scales) {
  const int t = threadIdx.x;

  if (blockIdx.x < 64) {
    __shared__ float pm[16][17];
    __shared__ float invs[16];
    const int col0 = blockIdx.x * 16;
    const int j = t & 15, rg = t >> 4;             // 16 cols x 16 row-groups
    float m = 0.f;
    for (int r = rg; r < 1024; r += 16)            // coalesced 64B rows
      m = fmaxf(m, fabsf(Tg[(size_t)r * DOUTN + col0 + j]));
    pm[rg][j] = m;
    __syncthreads();
    if (t < 16) {
      float mm = 0.f;
      #pragma unroll
      for (int k = 0; k < 16; ++k) mm = fmaxf(mm, pm[k][t]);
      scales[col0 + t] = mm * (1.f / 127.f);
      invs[t] = 127.f / mm;
    }
    __syncthreads();
    // pass 2: unit u = (pair p, half h, col j); thread does 4 units.
    #pragma unroll
    for (int ii = 0; ii < 4; ++ii) {
      int u = t + ii * 256;
      int p = u >> 5, h = (u >> 4) & 1, jj = u & 15;
      int c = 2 * p + h;
      int col = col0 + jj;
      const float* src = Tg + (size_t)c * KCODE * DOUTN + col;
      const float inv = invs[jj];
      unsigned int pk[4];
      #pragma unroll
      for (int q = 0; q < 4; ++q) {
        unsigned int w = 0;
        #pragma unroll
        for (int b = 0; b < 4; ++b) {
          float v = src[(size_t)(q * 4 + b) * DOUTN];   // k-strided, L2/L3-hot
          float r = rintf(v * inv);
          r = fminf(127.f, fmaxf(-127.f, r));
          w |= ((unsigned int)((int)r & 255)) << (8 * b);
        }
        pk[q] = w;
      }
      unsigned int* dst = (unsigned int*)(img + ((size_t)(col >> 6)) * 65536
                                          + p * 2048 + h * 1024 + (col & 63) * 16);
      dst[0] = pk[0]; dst[1] = pk[1]; dst[2] = pk[2]; dst[3] = pk[3];
    }
    return;
  }

  // ---- encode (R13 verbatim: xs-staged, quad-granular XOR swizzle) ----
  __shared__ __align__(16) float xs[8][SUBV * CBN];
  __shared__ int   sidxT[DEP * CBN];               // [d][c]
  __shared__ float svalT[DEP * (KCODE / 2) * CBN]; // [d][e][c]
  if (t < DEP * CBN) {
    int d = t >> 6, c = t & 63;
    sidxT[t] = split_idxs[c * DEP + d];
  }
  for (int i = t; i < DEP * (KCODE / 2) * CBN; i += 256) {
    int c = i & 63, de = i >> 6, d = de >> 3, e = de & 7;
    svalT[i] = split_vals[(c * DEP + d) * (KCODE / 2) + e];
  }
  const int n0 = (blockIdx.x - 64) * 8;
  const float4* xg = (const float4*)(x + (size_t)n0 * DOUTN);
  #pragma unroll
  for (int i = 0; i < 8; ++i) {                    // 8 rows * 256 float4/row
    int li = t + i * 256;
    int r = li >> 8, cpos = li & 255;
    float4 v = xg[r * 256 + cpos];
    int c = cpos >> 2, q = cpos & 3;
    *(float4*)&xs[r][c * SUBV + ((q ^ (c & 3)) << 2)] = v;
  }
  __syncthreads();
  const int c = t & 63, rg2 = t >> 6;
  #pragma unroll
  for (int i = 0; i < 2; ++i) {
    int nl = rg2 * 2 + i;
    int e = 0;
    #pragma unroll
    for (int d = 0; d < DEP; ++d) {
      int si = sidxT[d * 64 + c];
      float xv = xs[nl][c * SUBV + (((si >> 2) ^ (c & 3)) << 2) + (si & 3)];
      float th = svalT[(d * 8 + e) * 64 + c];
      e = 2 * e + (xv > th ? 1 : 0);
    }
    codes[(size_t)(n0 + nl) * CBN + c] = (unsigned char)e;
  }
}

// ---------------- kernel 2: one-hot i8 MFMA, 2 co-resident blocks/CU --------
// grid (16 colgroups, 32 rowgroups of 512) = 512 blocks; 512 thr = 8 waves;
// LDS = one full 64 KiB image -> TWO CO-RESIDENT blocks/CU with NO phase
// split and NO extra barriers (what made R16's bf16 version lose). Independent
// co-resident blocks desynchronize, so one block's epilogue writes drain under
// the other's mid-compute — the only remaining way to hide the ~10us write
// burst (intra-block spreading was neutral twice: R16, R18). Inner loop =
// R18 verbatim (row-phase split, i8 K=32 pair-MFMA, one-ahead code prefetch,
// wid-stagger, exact i32 accum, out = scale*acc + bias).
__global__ __launch_bounds__(512, 4) void maddness_mfma(
    const unsigned char* __restrict__ img, const float* __restrict__ scales,
    const float* __restrict__ bias, const unsigned char* __restrict__ codes,
    float* __restrict__ out) {
  __shared__ __align__(16) unsigned int Tb[16384];   // 64 KiB: [pair32][h2][col64][16B]

  const int t = threadIdx.x;
  const int wid = t >> 6, lane = t & 63, lrow = lane & 31, h = lane >> 5;
  const int g16 = blockIdx.x;
  const int n0 = blockIdx.y * 512;
  const unsigned char* img_g = img + (size_t)g16 * 65536;

  // stage 64 KiB linearly: 64 segs of 1024 B; 8 waves stage 8 each
  #pragma unroll
  for (int i = 0; i < 8; ++i) {
    int gs = wid * 8 + i;
    gld16(img_g + gs * 1024 + lane * 16, (char*)Tb + gs * 1024);
  }

  const char* tb = (const char*)Tb;
  const float sc0 = scales[g16 * 64 + lrow],      bb0 = bias[g16 * 64 + lrow];
  const float sc1 = scales[g16 * 64 + 32 + lrow], bb1 = bias[g16 * 64 + 32 + lrow];

  __syncthreads();                                  // the ONLY barrier

  #pragma unroll
  for (int rt = 0; rt < 2; ++rt) {                  // row-phase split (R18)
    const unsigned char* crow =
        codes + (size_t)(n0 + wid * 64 + rt * 32 + lrow) * CBN;

    i32x16 acc[2];
    #pragma unroll
    for (int ct = 0; ct < 2; ++ct)
      #pragma unroll
      for (int e = 0; e < 16; ++e) acc[ct][e] = 0;

    const int gg0 = wid & 7;
    unsigned long long qA = *(const unsigned long long*)(crow + gg0 * 8);

    #pragma unroll
    for (int g = 0; g < 8; ++g) {                   // 8 u64 code groups
      const int gcur = (wid + g) & 7;
      const unsigned long long q = qA;
      if (g < 7) {                                  // prefetch next codes
        const int ggn = (wid + g + 1) & 7;
        qA = *(const unsigned long long*)(crow + ggn * 8);
      }
      #pragma unroll
      for (int pp = 0; pp < 4; ++pp) {              // 4 pairs per group
        const int p = gcur * 4 + pp;                // codebooks 2p (h=0), 2p+1 (h=1)
        const char* pb = tb + p * 2048 + h * 1024 + lrow * 16;
        const i32x4 b0 = *(const i32x4*)pb;         // cols  0..31 (linear, no conflicts)
        const i32x4 b1 = *(const i32x4*)(pb + 512); // cols 32..63
        const unsigned c4 = (unsigned)(q >> ((pp * 2 + h) * 8)) & 15u;
        const unsigned long long tt = 1ULL << ((c4 & 7u) * 8u);
        union { unsigned long long q[2]; i32x4 v; } A;
        A.q[0] = (c4 < 8u) ? tt : 0ULL;
        A.q[1] = (c4 < 8u) ? 0ULL : tt;
        acc[0] = __builtin_amdgcn_mfma_i32_32x32x32_i8(A.v, b0, acc[0], 0, 0, 0);
        acc[1] = __builtin_amdgcn_mfma_i32_32x32x32_i8(A.v, b1, acc[1], 0, 0, 0);
      }
    }

    // write this row-phase now.
    // D layout col=lane&31, row=(reg&3)+8*(reg>>2)+4*(lane>>5)
    #pragma unroll
    for (int r = 0; r < 16; ++r) {
      int row = n0 + wid * 64 + rt * 32 + (r & 3) + 8 * (r >> 2) + 4 * h;
      float* orow = out + (size_t)row * DOUTN + g16 * 64 + lrow;
      orow[0]  = fmaf((float)acc[0][r], sc0, bb0);
      orow[32] = fmaf((float)acc[1][r], sc1, bb1);
    }
  }
}

extern "C" void kernel_launch(void* const* d_in, const int* in_sizes, int n_in,
                              void* d_out, int out_size, void* d_ws, size_t ws_size,
                              hipStream_t stream) {
  const float* x    = (const float*)d_in[0];
  const int*   sidx = (const int*)d_in[1];
  const float* sval = (const float*)d_in[2];
  const float* Tg   = (const float*)d_in[3];
  const float* bias = (const float*)d_in[4];
  float* out = (float*)d_out;
  unsigned char* codes  = (unsigned char*)d_ws;                      // 1 MiB
  unsigned char* img    = (unsigned char*)d_ws + (1 << 20);          // 1 MiB
  float*         scales = (float*)((char*)d_ws + (2 << 20));         // 4 KiB

  prep_k<<<64 + NN / 8, 256, 0, stream>>>(x, sidx, sval, Tg, codes, img, scales);
  maddness_mfma<<<dim3(16, 32), 512, 0, stream>>>(img, scales, bias, codes, out);
}

// Round 20
// 46.036 us; speedup vs baseline: 1.0220x; 1.0220x over previous
//
#include <hip/hip_runtime.h>

#define NN    16384
#define CBN   64
#define SUBV  16
#define KCODE 16
#define DOUTN 1024
#define DEP   4

typedef int   i32x4  __attribute__((ext_vector_type(4)));
typedef int   i32x16 __attribute__((ext_vector_type(16)));

// global -> LDS direct copy, 16B/lane. LDS dest wave-uniform (HW adds lane*16).
static __device__ __forceinline__ void gld16(const void* g, void* l) {
  __builtin_amdgcn_global_load_lds(
      (const __attribute__((address_space(1))) unsigned int*)g,
      (__attribute__((address_space(3))) unsigned int*)(uintptr_t)l, 16, 0, 0);
}

// ---------------- kernel 1: i8 table quantize + encode ----------------
// blocks [0,64) @512thr (only 256 active in quantize path): per-column absmax
// -> scale; quantize T to i8 into the linear img layout (R17 verbatim logic).
// blocks [64, 64+1024): encode 16 rows each with 512 thr — HALF the blocks of
// R18's encode, so split-table reload traffic (9 KiB/block) and per-block
// overheads halve; per-thread work identical (8 float4 stage, 2-row tree).
// xs 64 KiB + 9 KiB tables -> 2 blocks/CU = 16 waves/CU (same occupancy).
__global__ __launch_bounds__(512) void prep_k(
    const float* __restrict__ x, const int* __restrict__ split_idxs,
    const float* __restrict__ split_vals, const float* __restrict__ Tg,
    unsigned char* __restrict__ codes, unsigned char* __restrict__ img,
    float* __restrict__ scales) {
  const int t = threadIdx.x;

  if (blockIdx.x < 64) {
    if (t >= 256) return;                          // quantize uses 256 threads
    __shared__ float pm[16][17];
    __shared__ float invs[16];
    const int col0 = blockIdx.x * 16;
    const int j = t & 15, rg = t >> 4;             // 16 cols x 16 row-groups
    float m = 0.f;
    for (int r = rg; r < 1024; r += 16)            // coalesced 64B rows
      m = fmaxf(m, fabsf(Tg[(size_t)r * DOUTN + col0 + j]));
    pm[rg][j] = m;
    __syncthreads();
    if (t < 16) {
      float mm = 0.f;
      #pragma unroll
      for (int k = 0; k < 16; ++k) mm = fmaxf(mm, pm[k][t]);
      scales[col0 + t] = mm * (1.f / 127.f);
      invs[t] = 127.f / mm;
    }
    __syncthreads();
    // pass 2: unit u = (pair p, half h, col j); thread does 4 units.
    #pragma unroll
    for (int ii = 0; ii < 4; ++ii) {
      int u = t + ii * 256;
      int p = u >> 5, h = (u >> 4) & 1, jj = u & 15;
      int c = 2 * p + h;
      int col = col0 + jj;
      const float* src = Tg + (size_t)c * KCODE * DOUTN + col;
      const float inv = invs[jj];
      unsigned int pk[4];
      #pragma unroll
      for (int q = 0; q < 4; ++q) {
        unsigned int w = 0;
        #pragma unroll
        for (int b = 0; b < 4; ++b) {
          float v = src[(size_t)(q * 4 + b) * DOUTN];   // k-strided, L2/L3-hot
          float r = rintf(v * inv);
          r = fminf(127.f, fmaxf(-127.f, r));
          w |= ((unsigned int)((int)r & 255)) << (8 * b);
        }
        pk[q] = w;
      }
      unsigned int* dst = (unsigned int*)(img + ((size_t)(col >> 6)) * 65536
                                          + p * 2048 + h * 1024 + (col & 63) * 16);
      dst[0] = pk[0]; dst[1] = pk[1]; dst[2] = pk[2]; dst[3] = pk[3];
    }
    return;
  }

  // ---- encode: 16 rows/block, 512 thr (xs-staged, quad-granular XOR swz) ----
  __shared__ __align__(16) float xs[16][SUBV * CBN];
  __shared__ int   sidxT[DEP * CBN];               // [d][c]
  __shared__ float svalT[DEP * (KCODE / 2) * CBN]; // [d][e][c]
  if (t < DEP * CBN) {
    int d = t >> 6, c = t & 63;
    sidxT[t] = split_idxs[c * DEP + d];
  }
  for (int i = t; i < DEP * (KCODE / 2) * CBN; i += 512) {
    int c = i & 63, de = i >> 6, d = de >> 3, e = de & 7;
    svalT[i] = split_vals[(c * DEP + d) * (KCODE / 2) + e];
  }
  const int n0 = (blockIdx.x - 64) * 16;
  const float4* xg = (const float4*)(x + (size_t)n0 * DOUTN);
  #pragma unroll
  for (int i = 0; i < 8; ++i) {                    // 16 rows * 256 float4/row
    int li = t + i * 512;
    int r = li >> 8, cpos = li & 255;
    float4 v = xg[r * 256 + cpos];
    int c = cpos >> 2, q = cpos & 3;
    *(float4*)&xs[r][c * SUBV + ((q ^ (c & 3)) << 2)] = v;
  }
  __syncthreads();
  const int c = t & 63, rg2 = t >> 6;              // 8 row-groups x 2 rows
  #pragma unroll
  for (int i = 0; i < 2; ++i) {
    int nl = rg2 * 2 + i;
    int e = 0;
    #pragma unroll
    for (int d = 0; d < DEP; ++d) {
      int si = sidxT[d * 64 + c];
      float xv = xs[nl][c * SUBV + (((si >> 2) ^ (c & 3)) << 2) + (si & 3)];
      float th = svalT[(d * 8 + e) * 64 + c];
      e = 2 * e + (xv > th ? 1 : 0);
    }
    codes[(size_t)(n0 + nl) * CBN + c] = (unsigned char)e;
  }
}

// ---------------- kernel 2: one-hot i8 MFMA (R18 verbatim) ----------------
// grid (16 colgroups, 16 rowgroups) = 256 blocks = 1/CU; 1024 thr = 16 waves.
// 64 KiB linear gld16 stage, ONE barrier, free-run, wid-stagger, one-ahead
// code prefetch, i8 K=32 = 2 codebooks/MFMA, exact i32 accum, row-phase
// split, out = scale[col]*acc + bias[col]. Converged at ~30us (write-tail
// hiding null in R16/R18/R19).
__global__ __launch_bounds__(1024, 4) void maddness_mfma(
    const unsigned char* __restrict__ img, const float* __restrict__ scales,
    const float* __restrict__ bias, const unsigned char* __restrict__ codes,
    float* __restrict__ out) {
  __shared__ __align__(16) unsigned int Tb[16384];   // 64 KiB: [pair32][h2][col64][16B]

  const int t = threadIdx.x;
  const int wid = t >> 6, lane = t & 63, lrow = lane & 31, h = lane >> 5;
  const int g16 = blockIdx.x;
  const int n0 = blockIdx.y * 1024;
  const unsigned char* img_g = img + (size_t)g16 * 65536;

  // stage 64 KiB linearly: 64 segs of 1024 B; wave stages 4
  #pragma unroll
  for (int i = 0; i < 4; ++i) {
    int gs = wid * 4 + i;
    gld16(img_g + gs * 1024 + lane * 16, (char*)Tb + gs * 1024);
  }

  const char* tb = (const char*)Tb;
  const float sc0 = scales[g16 * 64 + lrow],      bb0 = bias[g16 * 64 + lrow];
  const float sc1 = scales[g16 * 64 + 32 + lrow], bb1 = bias[g16 * 64 + 32 + lrow];

  __syncthreads();                                  // the ONLY barrier

  #pragma unroll
  for (int rt = 0; rt < 2; ++rt) {                  // row-phase split
    const unsigned char* crow =
        codes + (size_t)(n0 + wid * 64 + rt * 32 + lrow) * CBN;

    i32x16 acc[2];
    #pragma unroll
    for (int ct = 0; ct < 2; ++ct)
      #pragma unroll
      for (int e = 0; e < 16; ++e) acc[ct][e] = 0;

    const int gg0 = wid & 7;
    unsigned long long qA = *(const unsigned long long*)(crow + gg0 * 8);

    #pragma unroll
    for (int g = 0; g < 8; ++g) {                   // 8 u64 code groups
      const int gcur = (wid + g) & 7;
      const unsigned long long q = qA;
      if (g < 7) {                                  // prefetch next codes
        const int ggn = (wid + g + 1) & 7;
        qA = *(const unsigned long long*)(crow + ggn * 8);
      }
      #pragma unroll
      for (int pp = 0; pp < 4; ++pp) {              // 4 pairs per group
        const int p = gcur * 4 + pp;                // codebooks 2p (h=0), 2p+1 (h=1)
        const char* pb = tb + p * 2048 + h * 1024 + lrow * 16;
        const i32x4 b0 = *(const i32x4*)pb;         // cols  0..31 (linear, no conflicts)
        const i32x4 b1 = *(const i32x4*)(pb + 512); // cols 32..63
        const unsigned c4 = (unsigned)(q >> ((pp * 2 + h) * 8)) & 15u;
        const unsigned long long tt = 1ULL << ((c4 & 7u) * 8u);
        union { unsigned long long q[2]; i32x4 v; } A;
        A.q[0] = (c4 < 8u) ? tt : 0ULL;
        A.q[1] = (c4 < 8u) ? 0ULL : tt;
        acc[0] = __builtin_amdgcn_mfma_i32_32x32x32_i8(A.v, b0, acc[0], 0, 0, 0);
        acc[1] = __builtin_amdgcn_mfma_i32_32x32x32_i8(A.v, b1, acc[1], 0, 0, 0);
      }
    }

    // write this row-phase now.
    // D layout col=lane&31, row=(reg&3)+8*(reg>>2)+4*(lane>>5)
    #pragma unroll
    for (int r = 0; r < 16; ++r) {
      int row = n0 + wid * 64 + rt * 32 + (r & 3) + 8 * (r >> 2) + 4 * h;
      float* orow = out + (size_t)row * DOUTN + g16 * 64 + lrow;
      orow[0]  = fmaf((float)acc[0][r], sc0, bb0);
      orow[32] = fmaf((float)acc[1][r], sc1, bb1);
    }
  }
}

extern "C" void kernel_launch(void* const* d_in, const int* in_sizes, int n_in,
                              void* d_out, int out_size, void* d_ws, size_t ws_size,
                              hipStream_t stream) {
  const float* x    = (const float*)d_in[0];
  const int*   sidx = (const int*)d_in[1];
  const float* sval = (const float*)d_in[2];
  const float* Tg   = (const float*)d_in[3];
  const float* bias = (const float*)d_in[4];
  float* out = (float*)d_out;
  unsigned char* codes  = (unsigned char*)d_ws;                      // 1 MiB
  unsigned char* img    = (unsigned char*)d_ws + (1 << 20);          // 1 MiB
  float*         scales = (float*)((char*)d_ws + (2 << 20));         // 4 KiB

  prep_k<<<64 + NN / 16, 512, 0, stream>>>(x, sidx, sval, Tg, codes, img, scales);
  maddness_mfma<<<dim3(16, 16), 1024, 0, stream>>>(img, scales, bias, codes, out);
}

// Round 21
// 45.469 us; speedup vs baseline: 1.0347x; 1.0125x over previous
//
#include <hip/hip_runtime.h>

#define NN    16384
#define CBN   64
#define SUBV  16
#define KCODE 16
#define DOUTN 1024
#define DEP   4

typedef int   i32x4  __attribute__((ext_vector_type(4)));
typedef int   i32x16 __attribute__((ext_vector_type(16)));

// global -> LDS direct copy, 16B/lane. LDS dest wave-uniform (HW adds lane*16).
static __device__ __forceinline__ void gld16(const void* g, void* l) {
  __builtin_amdgcn_global_load_lds(
      (const __attribute__((address_space(1))) unsigned int*)g,
      (__attribute__((address_space(3))) unsigned int*)(uintptr_t)l, 16, 0, 0);
}

// ---------------- kernel 1: i8 table quantize + encode (R20 verbatim) -------
__global__ __launch_bounds__(512) void prep_k(
    const float* __restrict__ x, const int* __restrict__ split_idxs,
    const float* __restrict__ split_vals, const float* __restrict__ Tg,
    unsigned char* __restrict__ codes, unsigned char* __restrict__ img,
    float* __restrict__ scales) {
  const int t = threadIdx.x;

  if (blockIdx.x < 64) {
    if (t >= 256) return;                          // quantize uses 256 threads
    __shared__ float pm[16][17];
    __shared__ float invs[16];
    const int col0 = blockIdx.x * 16;
    const int j = t & 15, rg = t >> 4;             // 16 cols x 16 row-groups
    float m = 0.f;
    for (int r = rg; r < 1024; r += 16)            // coalesced 64B rows
      m = fmaxf(m, fabsf(Tg[(size_t)r * DOUTN + col0 + j]));
    pm[rg][j] = m;
    __syncthreads();
    if (t < 16) {
      float mm = 0.f;
      #pragma unroll
      for (int k = 0; k < 16; ++k) mm = fmaxf(mm, pm[k][t]);
      scales[col0 + t] = mm * (1.f / 127.f);
      invs[t] = 127.f / mm;
    }
    __syncthreads();
    // pass 2: unit u = (pair p, half h, col j); thread does 4 units.
    #pragma unroll
    for (int ii = 0; ii < 4; ++ii) {
      int u = t + ii * 256;
      int p = u >> 5, h = (u >> 4) & 1, jj = u & 15;
      int c = 2 * p + h;
      int col = col0 + jj;
      const float* src = Tg + (size_t)c * KCODE * DOUTN + col;
      const float inv = invs[jj];
      unsigned int pk[4];
      #pragma unroll
      for (int q = 0; q < 4; ++q) {
        unsigned int w = 0;
        #pragma unroll
        for (int b = 0; b < 4; ++b) {
          float v = src[(size_t)(q * 4 + b) * DOUTN];   // k-strided, L2/L3-hot
          float r = rintf(v * inv);
          r = fminf(127.f, fmaxf(-127.f, r));
          w |= ((unsigned int)((int)r & 255)) << (8 * b);
        }
        pk[q] = w;
      }
      unsigned int* dst = (unsigned int*)(img + ((size_t)(col >> 6)) * 65536
                                          + p * 2048 + h * 1024 + (col & 63) * 16);
      dst[0] = pk[0]; dst[1] = pk[1]; dst[2] = pk[2]; dst[3] = pk[3];
    }
    return;
  }

  // ---- encode: 16 rows/block, 512 thr (xs-staged, quad-granular XOR swz) ----
  __shared__ __align__(16) float xs[16][SUBV * CBN];
  __shared__ int   sidxT[DEP * CBN];               // [d][c]
  __shared__ float svalT[DEP * (KCODE / 2) * CBN]; // [d][e][c]
  if (t < DEP * CBN) {
    int d = t >> 6, c = t & 63;
    sidxT[t] = split_idxs[c * DEP + d];
  }
  for (int i = t; i < DEP * (KCODE / 2) * CBN; i += 512) {
    int c = i & 63, de = i >> 6, d = de >> 3, e = de & 7;
    svalT[i] = split_vals[(c * DEP + d) * (KCODE / 2) + e];
  }
  const int n0 = (blockIdx.x - 64) * 16;
  const float4* xg = (const float4*)(x + (size_t)n0 * DOUTN);
  #pragma unroll
  for (int i = 0; i < 8; ++i) {                    // 16 rows * 256 float4/row
    int li = t + i * 512;
    int r = li >> 8, cpos = li & 255;
    float4 v = xg[r * 256 + cpos];
    int c = cpos >> 2, q = cpos & 3;
    *(float4*)&xs[r][c * SUBV + ((q ^ (c & 3)) << 2)] = v;
  }
  __syncthreads();
  const int c = t & 63, rg2 = t >> 6;              // 8 row-groups x 2 rows
  #pragma unroll
  for (int i = 0; i < 2; ++i) {
    int nl = rg2 * 2 + i;
    int e = 0;
    #pragma unroll
    for (int d = 0; d < DEP; ++d) {
      int si = sidxT[d * 64 + c];
      float xv = xs[nl][c * SUBV + (((si >> 2) ^ (c & 3)) << 2) + (si & 3)];
      float th = svalT[(d * 8 + e) * 64 + c];
      e = 2 * e + (xv > th ? 1 : 0);
    }
    codes[(size_t)(n0 + nl) * CBN + c] = (unsigned char)e;
  }
}

// ---------------- kernel 2: one-hot i8 MFMA + pinned early stores -----------
// R18/R20 structure verbatim EXCEPT: __builtin_amdgcn_sched_barrier(0) between
// the two rt phases. Hypothesis: the compiler was SINKING phase-A's stores
// past phase-B's compute (stores have no consumers), so R16/R18/R19's
// "early write" experiments never actually issued stores early — the barrier
// pins them before phase B, letting the 32 MiB burst drain under ~9us of
// MFMA/LDS/VALU instead of serializing at kernel end.
__global__ __launch_bounds__(1024, 4) void maddness_mfma(
    const unsigned char* __restrict__ img, const float* __restrict__ scales,
    const float* __restrict__ bias, const unsigned char* __restrict__ codes,
    float* __restrict__ out) {
  __shared__ __align__(16) unsigned int Tb[16384];   // 64 KiB: [pair32][h2][col64][16B]

  const int t = threadIdx.x;
  const int wid = t >> 6, lane = t & 63, lrow = lane & 31, h = lane >> 5;
  const int g16 = blockIdx.x;
  const int n0 = blockIdx.y * 1024;
  const unsigned char* img_g = img + (size_t)g16 * 65536;

  // stage 64 KiB linearly: 64 segs of 1024 B; wave stages 4
  #pragma unroll
  for (int i = 0; i < 4; ++i) {
    int gs = wid * 4 + i;
    gld16(img_g + gs * 1024 + lane * 16, (char*)Tb + gs * 1024);
  }

  const char* tb = (const char*)Tb;
  const float sc0 = scales[g16 * 64 + lrow],      bb0 = bias[g16 * 64 + lrow];
  const float sc1 = scales[g16 * 64 + 32 + lrow], bb1 = bias[g16 * 64 + 32 + lrow];

  __syncthreads();                                  // the ONLY barrier

  #pragma unroll
  for (int rt = 0; rt < 2; ++rt) {                  // row-phase split
    const unsigned char* crow =
        codes + (size_t)(n0 + wid * 64 + rt * 32 + lrow) * CBN;

    i32x16 acc[2];
    #pragma unroll
    for (int ct = 0; ct < 2; ++ct)
      #pragma unroll
      for (int e = 0; e < 16; ++e) acc[ct][e] = 0;

    const int gg0 = wid & 7;
    unsigned long long qA = *(const unsigned long long*)(crow + gg0 * 8);

    #pragma unroll
    for (int g = 0; g < 8; ++g) {                   // 8 u64 code groups
      const int gcur = (wid + g) & 7;
      const unsigned long long q = qA;
      if (g < 7) {                                  // prefetch next codes
        const int ggn = (wid + g + 1) & 7;
        qA = *(const unsigned long long*)(crow + ggn * 8);
      }
      #pragma unroll
      for (int pp = 0; pp < 4; ++pp) {              // 4 pairs per group
        const int p = gcur * 4 + pp;                // codebooks 2p (h=0), 2p+1 (h=1)
        const char* pb = tb + p * 2048 + h * 1024 + lrow * 16;
        const i32x4 b0 = *(const i32x4*)pb;         // cols  0..31 (linear, no conflicts)
        const i32x4 b1 = *(const i32x4*)(pb + 512); // cols 32..63
        const unsigned c4 = (unsigned)(q >> ((pp * 2 + h) * 8)) & 15u;
        const unsigned long long tt = 1ULL << ((c4 & 7u) * 8u);
        union { unsigned long long q[2]; i32x4 v; } A;
        A.q[0] = (c4 < 8u) ? tt : 0ULL;
        A.q[1] = (c4 < 8u) ? 0ULL : tt;
        acc[0] = __builtin_amdgcn_mfma_i32_32x32x32_i8(A.v, b0, acc[0], 0, 0, 0);
        acc[1] = __builtin_amdgcn_mfma_i32_32x32x32_i8(A.v, b1, acc[1], 0, 0, 0);
      }
    }

    // write this row-phase now.
    // D layout col=lane&31, row=(reg&3)+8*(reg>>2)+4*(lane>>5)
    #pragma unroll
    for (int r = 0; r < 16; ++r) {
      int row = n0 + wid * 64 + rt * 32 + (r & 3) + 8 * (r >> 2) + 4 * h;
      float* orow = out + (size_t)row * DOUTN + g16 * 64 + lrow;
      orow[0]  = fmaf((float)acc[0][r], sc0, bb0);
      orow[32] = fmaf((float)acc[1][r], sc1, bb1);
    }
    // pin phase-A stores BEFORE phase-B compute (compiler otherwise sinks
    // consumer-less stores to kernel end, defeating the overlap).
    __builtin_amdgcn_sched_barrier(0);
  }
}

extern "C" void kernel_launch(void* const* d_in, const int* in_sizes, int n_in,
                              void* d_out, int out_size, void* d_ws, size_t ws_size,
                              hipStream_t stream) {
  const float* x    = (const float*)d_in[0];
  const int*   sidx = (const int*)d_in[1];
  const float* sval = (const float*)d_in[2];
  const float* Tg   = (const float*)d_in[3];
  const float* bias = (const float*)d_in[4];
  float* out = (float*)d_out;
  unsigned char* codes  = (unsigned char*)d_ws;                      // 1 MiB
  unsigned char* img    = (unsigned char*)d_ws + (1 << 20);          // 1 MiB
  float*         scales = (float*)((char*)d_ws + (2 << 20));         // 4 KiB

  prep_k<<<64 + NN / 16, 512, 0, stream>>>(x, sidx, sval, Tg, codes, img, scales);
  maddness_mfma<<<dim3(16, 16), 1024, 0, stream>>>(img, scales, bias, codes, out);
}